// Round 15
// baseline (272.870 us; speedup 1.0000x reference)
//
#include <hip/hip_runtime.h>
#include <hip/hip_bf16.h>
#include <math.h>

#define B_  32
#define S_  512
#define D_  512
#define E_  8
#define H_  2048
#define O_  512

typedef __bf16 bf16x8 __attribute__((ext_vector_type(8)));
typedef float  f32x4  __attribute__((ext_vector_type(4)));

#define GL2LDS(src, dst) \
  __builtin_amdgcn_global_load_lds((const __attribute__((address_space(1))) void*)(src), \
                                   (__attribute__((address_space(3))) void*)(dst), 16, 0, 0)

#define MFMA16(a, b, c) __builtin_amdgcn_mfma_f32_16x16x32_bf16((a), (b), (c), 0, 0, 0)

// tanh-form GELU (proven r4-r14: absmax 3.9e-3 unchanged)
__device__ __forceinline__ float gelu_fast(float v) {
  float w = v * fmaf(v * v, 0.0713548162f, 1.5957691216f);
  float e = __expf(-w);
  return v * __builtin_amdgcn_rcpf(1.0f + e);
}

// =====================================================================
// Packed operand layout (r8/r9, HW-verified): [z][u = k/32][rows][64B],
// 16B slot within each 64B row pre-swizzled: phys_slot = ks ^ ((row>>1)&3).
// A 128-row slice of one u-unit is contiguous 8 KB.
// =====================================================================

// ---------------- cast x -> packed bf16 (xpack), fused attention scores ----
__global__ __launch_bounds__(256) void cast_score_kernel(
    const float* __restrict__ x, const float* __restrict__ attn_w,
    char* __restrict__ xpack, float* __restrict__ scores)
{
  const int t = threadIdx.x;
  const int r = t >> 5;
  const int cg = t & 31;
  const int row = blockIdx.x * 8 + r;     // global b*512+s
  const int bb = row >> 9, s = row & 511;
  const float* src  = x + (size_t)row * D_ + cg * 16;
  const float* wsrc = attn_w + cg * 16;
  char* xp = xpack + (size_t)bb * 524288 + s * 64;
  const int sx = (s >> 1) & 3;
  float acc = 0.f;
#pragma unroll
  for (int k = 0; k < 4; ++k) {
    const int d0 = cg * 16 + k * 4;
    float4 v  = *(const float4*)(src + k * 4);
    float4 wv = *(const float4*)(wsrc + k * 4);
    acc += v.x * wv.x + v.y * wv.y + v.z * wv.z + v.w * wv.w;
    ushort4 o;
    o.x = __builtin_bit_cast(unsigned short, __float2bfloat16(v.x));
    o.y = __builtin_bit_cast(unsigned short, __float2bfloat16(v.y));
    o.z = __builtin_bit_cast(unsigned short, __float2bfloat16(v.z));
    o.w = __builtin_bit_cast(unsigned short, __float2bfloat16(v.w));
    const int u = d0 >> 5;
    const int byte = u * 32768 + ((((d0 >> 3) & 3) ^ sx) << 4) + (d0 & 7) * 2;
    *(ushort4*)(xp + byte) = o;
  }
#pragma unroll
  for (int off = 16; off; off >>= 1) acc += __shfl_xor(acc, off);
  if (cg == 0) scores[row] = acc;
}

// ---------------- pool with inline softmax: pooled[b,d] = sum_s aw[b,s]*x[b,s,d] ----
// Each block recomputes the batch softmax from scores (2KB read, cheap) ->
// one less serial launch + no aw global roundtrip.
__global__ __launch_bounds__(512) void pool_kernel(
    const float* __restrict__ x, const float* __restrict__ scores,
    float* __restrict__ pooled)
{
  __shared__ float awsh[512];
  __shared__ float red[8];
  __shared__ float mm, ss;
  __shared__ float sm[4][128];
  const int t = threadIdx.x;
  const int b = blockIdx.y;
  float v = scores[b * S_ + t];
  float m = v;
#pragma unroll
  for (int off = 32; off; off >>= 1) m = fmaxf(m, __shfl_xor(m, off));
  if ((t & 63) == 0) red[t >> 6] = m;
  __syncthreads();
  if (t == 0) {
    float a = red[0];
    for (int i = 1; i < 8; ++i) a = fmaxf(a, red[i]);
    mm = a;
  }
  __syncthreads();
  float e = expf(v - mm);
  float s = e;
#pragma unroll
  for (int off = 32; off; off >>= 1) s += __shfl_xor(s, off);
  if ((t & 63) == 0) red[t >> 6] = s;
  __syncthreads();
  if (t == 0) {
    float a = 0.f;
    for (int i = 0; i < 8; ++i) a += red[i];
    ss = 1.f / a;
  }
  __syncthreads();
  awsh[t] = e * ss;
  __syncthreads();

  const int dl = t & 127;
  const int sh = t >> 7;
  const int d = blockIdx.x * 128 + dl;
  const float* xp = x + (size_t)b * S_ * D_ + d;
  float acc = 0.f;
#pragma unroll 4
  for (int s2 = sh; s2 < S_; s2 += 4)
    acc = fmaf(awsh[s2], xp[(size_t)s2 * D_], acc);
  if (sh) sm[sh][dl] = acc;
  __syncthreads();
  if (sh == 0) pooled[b * D_ + d] = acc + sm[1][dl] + sm[2][dl] + sm[3][dl];
}

// ---------------- gates + top-2 + renorm + expert-sort ----------------
__global__ __launch_bounds__(256) void gate_psort_kernel(
    const float* __restrict__ pooled, const float* __restrict__ gate_w,
    const float* __restrict__ gate_b, int* __restrict__ gidx, float* __restrict__ gwt,
    int* __restrict__ psort)
{
  __shared__ float gl[32][8];
  const int t = threadIdx.x;
  const int b = t >> 3, ee = t & 7;
  float z = gate_b[ee];
  const float* pb = pooled + b * D_;
  for (int d = 0; d < D_; ++d) z = fmaf(pb[d], gate_w[d * E_ + ee], z);
  gl[b][ee] = z;
  __syncthreads();
  if (t < 32) {
    float ge[8];
    float zmax = gl[t][0];
    for (int i = 1; i < 8; ++i) zmax = fmaxf(zmax, gl[t][i]);
    float zs = 0.f;
    for (int i = 0; i < 8; ++i) { ge[i] = expf(gl[t][i] - zmax); zs += ge[i]; }
    for (int i = 0; i < 8; ++i) ge[i] /= zs;
    int i0 = 0;
    for (int i = 1; i < 8; ++i) if (ge[i] > ge[i0]) i0 = i;
    int i1 = -1;
    for (int i = 0; i < 8; ++i) if (i != i0 && (i1 < 0 || ge[i] > ge[i1])) i1 = i;
    float denom = ge[i0] + ge[i1] + 1e-9f;
    gidx[t * 2 + 0] = i0; gidx[t * 2 + 1] = i1;
    gwt[t * 2 + 0] = ge[i0] / denom; gwt[t * 2 + 1] = ge[i1] / denom;
  }
  __syncthreads();
  if (t == 0) {
    int cnt[E_] = {}, pos[E_];
    for (int p = 0; p < 2 * B_; ++p) cnt[gidx[p]]++;
    int s = 0;
    for (int e2 = 0; e2 < E_; ++e2) { pos[e2] = s; s += cnt[e2]; }
    for (int p = 0; p < 2 * B_; ++p) psort[pos[gidx[p]]++] = p;
  }
}

// ---------------- weight pack: [z][R k][C rows] f32 -> packed bf16 ----------------
__global__ void pack_w_kernel(const float* __restrict__ in, char* __restrict__ outp,
                              int R, int C)
{
  __shared__ float tile[32][33];
  const int z = blockIdx.z;
  const float* inz = in + (size_t)z * R * C;
  const int c0 = blockIdx.x * 32, r0 = blockIdx.y * 32;
  const int tx = threadIdx.x, ty = threadIdx.y;
#pragma unroll
  for (int jj = 0; jj < 4; ++jj) {
    int r = r0 + ty + jj * 8;
    tile[ty + jj * 8][tx] = inz[(size_t)r * C + c0 + tx];
  }
  __syncthreads();
  const int k = r0 + tx;
  const int u = k >> 5;                                 // constant over tile
  const int PAN = C * 64;
  char* oz = outp + (size_t)z * R * C * 2 + (size_t)u * PAN;
  const int kslot = (k >> 3) & 3;
  const int kbyte = (k & 7) * 2;
#pragma unroll
  for (int jj = 0; jj < 4; ++jj) {
    const int row = c0 + ty + jj * 8;
    const int byte = row * 64 + ((kslot ^ ((row >> 1) & 3)) << 4) + kbyte;
    *(ushort*)(oz + byte) =
        __builtin_bit_cast(unsigned short, __float2bfloat16(tile[tx][ty + jj * 8]));
  }
}

// =====================================================================
// GEMM core v9: 128 x 128 x BK=64, 128 threads = 2 WAVES.
// Wave w owns m-half (64 A rows) x FULL n (128 B cols): acc[4][8].
// Per block-tile reads: A 8/wave (no duplication) + B 16/wave = 48 b128
// total (vs r12's 64) -> LDS-unit time/tile ~1070 -> ~880 cyc, and
// 32KB x 4 = 128KB LDS -> 4 resident blocks/CU (launch_bounds(128,2),
// ~200 VGPR). Same m97 drain loop: {stage 16 GL2LDS | vmcnt(0) | barrier |
// reads+MFMA | barrier}. LDS: A [2kh][128 rows][64B] at 0, B same at 16K.
// Read swizzle phys_slot = ks ^ ((lr>>1)&3) (frag base rows mult of 16).
// =====================================================================
__device__ __forceinline__ void gemm_core_v9(const char* __restrict__ Ag, const char* __restrict__ Bg,
                                             const size_t unitA, const size_t unitB,
                                             const int NT, char* lds, f32x4 (&acc)[4][8])
{
  const int tid = threadIdx.x;
  const int l = tid & 63;
  const int w = tid >> 6;                 // wave 0..1 = m-half
  const int lr = l & 15;
  const int ks = (l >> 4) & 3;
  const int swz = ((ks ^ ((lr >> 1) & 3)) << 4);
  const int abase = (w * 64 + lr) * 64 + swz;             // + m*1024 + kh*8192
  const int bbase = 16384 + lr * 64 + swz;                // + n*1024 + kh*8192
  const int dst = tid * 16;                               // 2KB per instruction round

#pragma unroll 1
  for (int t = 0; t < NT; ++t) {
    const char* a0 = Ag + (size_t)(2 * t)     * unitA;
    const char* a1 = Ag + (size_t)(2 * t + 1) * unitA;
    const char* b0 = Bg + (size_t)(2 * t)     * unitB;
    const char* b1 = Bg + (size_t)(2 * t + 1) * unitB;
#pragma unroll
    for (int c = 0; c < 4; ++c) {
      GL2LDS(a0 + c * 2048 + dst, lds + c * 2048 + dst);
      GL2LDS(a1 + c * 2048 + dst, lds + 8192 + c * 2048 + dst);
      GL2LDS(b0 + c * 2048 + dst, lds + 16384 + c * 2048 + dst);
      GL2LDS(b1 + c * 2048 + dst, lds + 24576 + c * 2048 + dst);
    }
    asm volatile("s_waitcnt vmcnt(0)" ::: "memory");
    __builtin_amdgcn_s_barrier();

#pragma unroll
    for (int kh = 0; kh < 2; ++kh) {
      bf16x8 bv[8];
#pragma unroll
      for (int n = 0; n < 8; ++n)
        bv[n] = *(const bf16x8*)(lds + 16384 + kh * 8192 + (lr + n * 16) * 64 + swz);
#pragma unroll
      for (int m = 0; m < 4; ++m) {
        const bf16x8 af = *(const bf16x8*)(lds + kh * 8192 + abase + m * 1024);
#pragma unroll
        for (int n = 0; n < 8; ++n)
          acc[m][n] = MFMA16(af, bv[n], acc[m][n]);
      }
    }
    __builtin_amdgcn_s_barrier();   // all reads done -> next stage may overwrite
  }
}

// ---------------- GEMM1: Hpack = gelu(x @ w1 + b1)  (A = W1 h-rows) ----------------
__global__ __launch_bounds__(128, 2) void gemm1_kernel(
    const char* __restrict__ xpack, const char* __restrict__ W1pack,
    const float* __restrict__ b1, char* __restrict__ Hpack,
    const int* __restrict__ gidx, const int* __restrict__ psort)
{
  __shared__ char lds[32768];
  const int P = blockIdx.x;                 // 4096
  const int L = (P & 7) * 512 + (P >> 3);   // bijective XCD chunk remap
  const int p = psort[L >> 6];              // 64 tiles/pair, pair-clustered per XCD
  const int tl = L & 63;
  const int b = p >> 1;
  const int e = gidx[p];
  const int h0 = (tl >> 2) * 128;           // 16 h-tiles
  const int s0 = (tl & 3) * 128;            // 4 s-tiles
  const char* Ag = W1pack + (size_t)e * 2097152 + h0 * 64;  // unit stride 131072
  const char* Bg = xpack + (size_t)b * 524288 + s0 * 64;    // unit stride 32768
  f32x4 acc[4][8] = {};
  gemm_core_v9(Ag, Bg, 131072, 32768, D_ / 64, lds, acc);

  const int tid = threadIdx.x, l = tid & 63, w = tid >> 6;
  const int lr = l & 15, q4 = ((l >> 4) & 3) << 2;
  const float* b1e = b1 + (size_t)e * H_ + h0;
  char* Hp = Hpack + (size_t)p * 2097152;
#pragma unroll
  for (int m = 0; m < 4; ++m) {
    const int hl = w * 64 + m * 16 + q4;            // feature offset (mult of 4)
    const int h = h0 + hl;
    const int uh = h >> 5;
    const int hslot = (h >> 3) & 3;
    const int hbyte = (h & 7) * 2;
    const float4 bias = *(const float4*)(b1e + hl);
#pragma unroll
    for (int n = 0; n < 8; ++n) {
      const int sl = s0 + n * 16 + lr;              // s row
      ushort4 ov;
      ov.x = __builtin_bit_cast(unsigned short, __float2bfloat16(gelu_fast(acc[m][n][0] + bias.x)));
      ov.y = __builtin_bit_cast(unsigned short, __float2bfloat16(gelu_fast(acc[m][n][1] + bias.y)));
      ov.z = __builtin_bit_cast(unsigned short, __float2bfloat16(gelu_fast(acc[m][n][2] + bias.z)));
      ov.w = __builtin_bit_cast(unsigned short, __float2bfloat16(gelu_fast(acc[m][n][3] + bias.w)));
      const int byte = uh * 32768 + sl * 64 + ((hslot ^ ((sl >> 1) & 3)) << 4) + hbyte;
      *(ushort4*)(Hp + byte) = ov;
    }
  }
}

// ---------------- GEMM2: out += gw * gelu(H @ w2 + b2)  (A = Hpack s-rows) ----------------
// j along s, 16 lanes cover 16 consecutive o -> line-friendly atomics
// (r7/r12-verified: WRITE 65 MB). 2 deterministic f32 atomic terms per output.
__global__ __launch_bounds__(128, 2) void gemm2_kernel(
    const char* __restrict__ Hpack, const char* __restrict__ W2pack,
    const float* __restrict__ b2, float* __restrict__ out,
    const int* __restrict__ gidx, const float* __restrict__ gwt,
    const int* __restrict__ psort)
{
  __shared__ char lds[32768];
  const int P = blockIdx.x;                 // 1024 (exactly 4/CU)
  const int L = (P & 7) * 128 + (P >> 3);
  const int p = psort[L >> 4];              // 16 tiles/pair, expert-clustered per XCD
  const int tl = L & 15;
  const int b = p >> 1;
  const int e = gidx[p];
  const float gw = gwt[p];
  const int o0 = (tl >> 2) * 128;           // 4 o-tiles (n-axis)
  const int s0 = (tl & 3) * 128;            // 4 s-tiles (m-axis)
  const char* Ag = Hpack + (size_t)p * 2097152 + s0 * 64;   // unit stride 32768
  const char* Bg = W2pack + (size_t)e * 2097152 + o0 * 64;  // unit stride 32768
  f32x4 acc[4][8] = {};
  gemm_core_v9(Ag, Bg, 32768, 32768, H_ / 64, lds, acc);

  const int tid = threadIdx.x, l = tid & 63, w = tid >> 6;
  const int lr = l & 15, q4 = ((l >> 4) & 3) << 2;
  const float* b2e = b2 + (size_t)e * O_ + o0;
#pragma unroll
  for (int m = 0; m < 4; ++m) {
    const int sl = s0 + w * 64 + m * 16 + q4;       // s base for j=0..3
#pragma unroll
    for (int n = 0; n < 8; ++n) {
      const int ol = n * 16 + lr;                   // o (16 consecutive per lane group)
      const float bias = b2e[ol];
      float* dstp = out + ((size_t)b * S_ + sl) * O_ + o0 + ol;
#pragma unroll
      for (int j = 0; j < 4; ++j)
        atomicAdd(dstp + (size_t)j * O_, gelu_fast(acc[m][n][j] + bias) * gw);
    }
  }
}

// ---------------- sentinel (ws too small signal) ----------------
__global__ void sentinel_kernel(float* out, int n) {
  int i = blockIdx.x * blockDim.x + threadIdx.x;
  for (; i < n; i += gridDim.x * blockDim.x) out[i] = 1.0e6f;
}

extern "C" void kernel_launch(void* const* d_in, const int* in_sizes, int n_in,
                              void* d_out, int out_size, void* d_ws, size_t ws_size,
                              hipStream_t stream)
{
  const float* x      = (const float*)d_in[0];
  const float* attn_w = (const float*)d_in[1];
  // d_in[2] = attn_b: scalar, softmax-invariant -> unused
  const float* gate_w = (const float*)d_in[3];
  const float* gate_b = (const float*)d_in[4];
  const float* w1     = (const float*)d_in[5];
  const float* b1     = (const float*)d_in[6];
  const float* w2     = (const float*)d_in[7];
  const float* b2     = (const float*)d_in[8];
  float* out = (float*)d_out;

  char* ws = (char*)d_ws;
  const size_t OFF_GIDX = 0;
  const size_t OFF_GWT  = 256;
  const size_t OFF_PSRT = 512;
  const size_t OFF_X    = 1024;
  const size_t SZ_X     = (size_t)B_ * S_ * D_ * 2;   // 16 MB (xpack)
  const size_t OFF_W1T  = OFF_X + SZ_X;
  const size_t SZ_W1T   = (size_t)E_ * H_ * D_ * 2;   // 16 MB (W1pack)
  const size_t OFF_W2T  = OFF_W1T + SZ_W1T;
  const size_t SZ_W2T   = (size_t)E_ * O_ * H_ * 2;   // 16 MB (W2pack)
  const size_t OFF_H    = OFF_W2T + SZ_W2T;
  const size_t PAIR_H   = (size_t)S_ * H_ * 2;        // 2 MB per pair (Hpack)

  if (OFF_H + 64 * PAIR_H > ws_size) {
    hipLaunchKernelGGL(sentinel_kernel, dim3(256), dim3(256), 0, stream, out, out_size);
    return;
  }

  int*   gidx   = (int*)(ws + OFF_GIDX);
  float* gwt    = (float*)(ws + OFF_GWT);
  int*   psort  = (int*)(ws + OFF_PSRT);
  char*  xpack  = ws + OFF_X;
  char*  W1pack = ws + OFF_W1T;
  char*  W2pack = ws + OFF_W2T;
  char*  Hpack  = ws + OFF_H;
  // pool-chain scratch overlaid on Hpack region (consumed before gemm1 writes it)
  float* scores = (float*)(ws + OFF_H);            // 64 KB
  float* pooled = (float*)(ws + OFF_H + 131072);   // 64 KB

  hipLaunchKernelGGL(cast_score_kernel, dim3(B_ * S_ / 8), dim3(256), 0, stream,
                     x, attn_w, xpack, scores);
  hipLaunchKernelGGL(pool_kernel, dim3(4, B_), dim3(512), 0, stream, x, scores, pooled);
  hipLaunchKernelGGL(gate_psort_kernel, dim3(1), dim3(256), 0, stream,
                     pooled, gate_w, gate_b, gidx, gwt, psort);
  hipLaunchKernelGGL(pack_w_kernel, dim3(H_ / 32, D_ / 32, E_), dim3(32, 8), 0, stream,
                     w1, W1pack, D_, H_);
  hipLaunchKernelGGL(pack_w_kernel, dim3(O_ / 32, H_ / 32, E_), dim3(32, 8), 0, stream,
                     w2, W2pack, H_, O_);
  hipMemsetAsync(d_out, 0, (size_t)out_size * sizeof(float), stream);

  hipLaunchKernelGGL(gemm1_kernel, dim3(4096), dim3(128), 0, stream,
                     xpack, W1pack, b1, Hpack, gidx, psort);
  hipLaunchKernelGGL(gemm2_kernel, dim3(1024), dim3(128), 0, stream,
                     Hpack, W2pack, b2, out, gidx, gwt, psort);
}

// Round 16
// 260.481 us; speedup vs baseline: 1.0476x; 1.0476x over previous
//
#include <hip/hip_runtime.h>
#include <hip/hip_bf16.h>
#include <math.h>

#define B_  32
#define S_  512
#define D_  512
#define E_  8
#define H_  2048
#define O_  512

typedef __bf16 bf16x8 __attribute__((ext_vector_type(8)));
typedef float  f32x4  __attribute__((ext_vector_type(4)));

#define GL2LDS(src, dst) \
  __builtin_amdgcn_global_load_lds((const __attribute__((address_space(1))) void*)(src), \
                                   (__attribute__((address_space(3))) void*)(dst), 16, 0, 0)

#define MFMA16(a, b, c) __builtin_amdgcn_mfma_f32_16x16x32_bf16((a), (b), (c), 0, 0, 0)

// tanh-form GELU (proven r4-r15: absmax 3.9e-3 unchanged)
__device__ __forceinline__ float gelu_fast(float v) {
  float w = v * fmaf(v * v, 0.0713548162f, 1.5957691216f);
  float e = __expf(-w);
  return v * __builtin_amdgcn_rcpf(1.0f + e);
}

// =====================================================================
// Packed operand layout (r8/r9, HW-verified): [z][u = k/32][rows][64B],
// 16B slot within each 64B row pre-swizzled: phys_slot = ks ^ ((row>>1)&3).
// A 128-row slice of one u-unit is contiguous 8 KB.
// =====================================================================

// ---------------- cast x -> packed bf16 (xpack), fused attention scores ----
__global__ __launch_bounds__(256) void cast_score_kernel(
    const float* __restrict__ x, const float* __restrict__ attn_w,
    char* __restrict__ xpack, float* __restrict__ scores)
{
  const int t = threadIdx.x;
  const int r = t >> 5;
  const int cg = t & 31;
  const int row = blockIdx.x * 8 + r;     // global b*512+s
  const int bb = row >> 9, s = row & 511;
  const float* src  = x + (size_t)row * D_ + cg * 16;
  const float* wsrc = attn_w + cg * 16;
  char* xp = xpack + (size_t)bb * 524288 + s * 64;
  const int sx = (s >> 1) & 3;
  float acc = 0.f;
#pragma unroll
  for (int k = 0; k < 4; ++k) {
    const int d0 = cg * 16 + k * 4;
    float4 v  = *(const float4*)(src + k * 4);
    float4 wv = *(const float4*)(wsrc + k * 4);
    acc += v.x * wv.x + v.y * wv.y + v.z * wv.z + v.w * wv.w;
    ushort4 o;
    o.x = __builtin_bit_cast(unsigned short, __float2bfloat16(v.x));
    o.y = __builtin_bit_cast(unsigned short, __float2bfloat16(v.y));
    o.z = __builtin_bit_cast(unsigned short, __float2bfloat16(v.z));
    o.w = __builtin_bit_cast(unsigned short, __float2bfloat16(v.w));
    const int u = d0 >> 5;
    const int byte = u * 32768 + ((((d0 >> 3) & 3) ^ sx) << 4) + (d0 & 7) * 2;
    *(ushort4*)(xp + byte) = o;
  }
#pragma unroll
  for (int off = 16; off; off >>= 1) acc += __shfl_xor(acc, off);
  if (cg == 0) scores[row] = acc;
}

// ---------------- pool with inline softmax (r15, verified) ----------------
__global__ __launch_bounds__(512) void pool_kernel(
    const float* __restrict__ x, const float* __restrict__ scores,
    float* __restrict__ pooled)
{
  __shared__ float awsh[512];
  __shared__ float red[8];
  __shared__ float mm, ss;
  __shared__ float sm[4][128];
  const int t = threadIdx.x;
  const int b = blockIdx.y;
  float v = scores[b * S_ + t];
  float m = v;
#pragma unroll
  for (int off = 32; off; off >>= 1) m = fmaxf(m, __shfl_xor(m, off));
  if ((t & 63) == 0) red[t >> 6] = m;
  __syncthreads();
  if (t == 0) {
    float a = red[0];
    for (int i = 1; i < 8; ++i) a = fmaxf(a, red[i]);
    mm = a;
  }
  __syncthreads();
  float e = expf(v - mm);
  float s = e;
#pragma unroll
  for (int off = 32; off; off >>= 1) s += __shfl_xor(s, off);
  if ((t & 63) == 0) red[t >> 6] = s;
  __syncthreads();
  if (t == 0) {
    float a = 0.f;
    for (int i = 0; i < 8; ++i) a += red[i];
    ss = 1.f / a;
  }
  __syncthreads();
  awsh[t] = e * ss;
  __syncthreads();

  const int dl = t & 127;
  const int sh = t >> 7;
  const int d = blockIdx.x * 128 + dl;
  const float* xp = x + (size_t)b * S_ * D_ + d;
  float acc = 0.f;
#pragma unroll 4
  for (int s2 = sh; s2 < S_; s2 += 4)
    acc = fmaf(awsh[s2], xp[(size_t)s2 * D_], acc);
  if (sh) sm[sh][dl] = acc;
  __syncthreads();
  if (sh == 0) pooled[b * D_ + d] = acc + sm[1][dl] + sm[2][dl] + sm[3][dl];
}

// ---------------- gates + top-2 + renorm + expert-sort ----------------
__global__ __launch_bounds__(256) void gate_psort_kernel(
    const float* __restrict__ pooled, const float* __restrict__ gate_w,
    const float* __restrict__ gate_b, int* __restrict__ gidx, float* __restrict__ gwt,
    int* __restrict__ psort)
{
  __shared__ float gl[32][8];
  const int t = threadIdx.x;
  const int b = t >> 3, ee = t & 7;
  float z = gate_b[ee];
  const float* pb = pooled + b * D_;
  for (int d = 0; d < D_; ++d) z = fmaf(pb[d], gate_w[d * E_ + ee], z);
  gl[b][ee] = z;
  __syncthreads();
  if (t < 32) {
    float ge[8];
    float zmax = gl[t][0];
    for (int i = 1; i < 8; ++i) zmax = fmaxf(zmax, gl[t][i]);
    float zs = 0.f;
    for (int i = 0; i < 8; ++i) { ge[i] = expf(gl[t][i] - zmax); zs += ge[i]; }
    for (int i = 0; i < 8; ++i) ge[i] /= zs;
    int i0 = 0;
    for (int i = 1; i < 8; ++i) if (ge[i] > ge[i0]) i0 = i;
    int i1 = -1;
    for (int i = 0; i < 8; ++i) if (i != i0 && (i1 < 0 || ge[i] > ge[i1])) i1 = i;
    float denom = ge[i0] + ge[i1] + 1e-9f;
    gidx[t * 2 + 0] = i0; gidx[t * 2 + 1] = i1;
    gwt[t * 2 + 0] = ge[i0] / denom; gwt[t * 2 + 1] = ge[i1] / denom;
  }
  __syncthreads();
  if (t == 0) {
    int cnt[E_] = {}, pos[E_];
    for (int p = 0; p < 2 * B_; ++p) cnt[gidx[p]]++;
    int s = 0;
    for (int e2 = 0; e2 < E_; ++e2) { pos[e2] = s; s += cnt[e2]; }
    for (int p = 0; p < 2 * B_; ++p) psort[pos[gidx[p]]++] = p;
  }
}

// ---------------- weight pack: [z][R k][C rows] f32 -> packed bf16 ----------------
__global__ void pack_w_kernel(const float* __restrict__ in, char* __restrict__ outp,
                              int R, int C)
{
  __shared__ float tile[32][33];
  const int z = blockIdx.z;
  const float* inz = in + (size_t)z * R * C;
  const int c0 = blockIdx.x * 32, r0 = blockIdx.y * 32;
  const int tx = threadIdx.x, ty = threadIdx.y;
#pragma unroll
  for (int jj = 0; jj < 4; ++jj) {
    int r = r0 + ty + jj * 8;
    tile[ty + jj * 8][tx] = inz[(size_t)r * C + c0 + tx];
  }
  __syncthreads();
  const int k = r0 + tx;
  const int u = k >> 5;                                 // constant over tile
  const int PAN = C * 64;
  char* oz = outp + (size_t)z * R * C * 2 + (size_t)u * PAN;
  const int kslot = (k >> 3) & 3;
  const int kbyte = (k & 7) * 2;
#pragma unroll
  for (int jj = 0; jj < 4; ++jj) {
    const int row = c0 + ty + jj * 8;
    const int byte = row * 64 + ((kslot ^ ((row >> 1) & 3)) << 4) + kbyte;
    *(ushort*)(oz + byte) =
        __builtin_bit_cast(unsigned short, __float2bfloat16(tile[tx][ty + jj * 8]));
  }
}

// =====================================================================
// GEMM core v10: 128 x 128 x BK=64, 256 thr = 4 waves (wm=w>>1, wn=w&1),
// per-wave 64x64 acc[4][4].  A staged via GL2LDS into a SINGLE 16KB buffer
// ([2 kh][128 rows][64B]); B loaded GLOBAL->VGPR per wave (8 bf16x8 frags
// from the L2-resident packed panel, same per-lane 16B pattern the DMA
// used).  Halves the LDS-unit load per tile (~1070 -> ~535 cyc) at equal
// residency: launch_bounds(256,3) -> 3 blocks/CU (r12's proven regime).
// Drain loop: {4 GL2LDS + 8 B-loads | vmcnt(0) | barrier | 8 ds_reads +
// 32 MFMA | barrier}. Read swizzle phys_slot = ks ^ ((lr>>1)&3).
// =====================================================================
__device__ __forceinline__ void gemm_core_v10(const char* __restrict__ Ag, const char* __restrict__ Bg,
                                              const size_t unitA, const size_t unitB,
                                              const int NT, char* lds, f32x4 (&acc)[4][4])
{
  const int tid = threadIdx.x;
  const int l = tid & 63;
  const int w = tid >> 6;
  const int wm = w >> 1;
  const int wn = w & 1;
  const int lr = l & 15;
  const int ks = (l >> 4) & 3;
  const int swz = ((ks ^ ((lr >> 1) & 3)) << 4);
  const int abase = wm * 4096 + lr * 64 + swz;            // + m*1024 + kh*8192
  const int bloff = (wn * 64 + lr) * 64 + swz;            // + n*1024 within unit
  const int dst = tid * 16;                               // 4KB per instruction round

#pragma unroll 1
  for (int t = 0; t < NT; ++t) {
    const char* a0 = Ag + (size_t)(2 * t)     * unitA;
    const char* a1 = Ag + (size_t)(2 * t + 1) * unitA;
    const char* b0 = Bg + (size_t)(2 * t)     * unitB + bloff;
    const char* b1 = Bg + (size_t)(2 * t + 1) * unitB + bloff;
    GL2LDS(a0 + dst, lds + dst);          GL2LDS(a0 + 4096 + dst, lds + 4096 + dst);
    GL2LDS(a1 + dst, lds + 8192 + dst);   GL2LDS(a1 + 4096 + dst, lds + 12288 + dst);
    bf16x8 bv0[4], bv1[4];
#pragma unroll
    for (int n = 0; n < 4; ++n) {
      bv0[n] = *(const bf16x8*)(b0 + n * 1024);
      bv1[n] = *(const bf16x8*)(b1 + n * 1024);
    }
    asm volatile("s_waitcnt vmcnt(0)" ::: "memory");
    __builtin_amdgcn_s_barrier();

    bf16x8 a0f[4], a1f[4];
#pragma unroll
    for (int m = 0; m < 4; ++m) {
      a0f[m] = *(const bf16x8*)(lds + abase + m * 1024);
      a1f[m] = *(const bf16x8*)(lds + 8192 + abase + m * 1024);
    }
#pragma unroll
    for (int m = 0; m < 4; ++m)
#pragma unroll
      for (int n = 0; n < 4; ++n) {
        acc[m][n] = MFMA16(a0f[m], bv0[n], acc[m][n]);
        acc[m][n] = MFMA16(a1f[m], bv1[n], acc[m][n]);
      }
    __builtin_amdgcn_s_barrier();   // all A reads done -> next stage may overwrite
  }
}

// ---------------- GEMM1: Hpack = gelu(x @ w1 + b1)  (A = W1 h-rows) ----------------
__global__ __launch_bounds__(256, 3) void gemm1_kernel(
    const char* __restrict__ xpack, const char* __restrict__ W1pack,
    const float* __restrict__ b1, char* __restrict__ Hpack,
    const int* __restrict__ gidx, const int* __restrict__ psort)
{
  __shared__ char lds[16384];
  const int P = blockIdx.x;                 // 4096
  const int L = (P & 7) * 512 + (P >> 3);   // bijective XCD chunk remap
  const int p = psort[L >> 6];              // 64 tiles/pair, pair-clustered per XCD
  const int tl = L & 63;
  const int b = p >> 1;
  const int e = gidx[p];
  const int h0 = (tl >> 2) * 128;           // 16 h-tiles
  const int s0 = (tl & 3) * 128;            // 4 s-tiles
  const char* Ag = W1pack + (size_t)e * 2097152 + h0 * 64;  // unit stride 131072
  const char* Bg = xpack + (size_t)b * 524288 + s0 * 64;    // unit stride 32768
  f32x4 acc[4][4] = {};
  gemm_core_v10(Ag, Bg, 131072, 32768, D_ / 64, lds, acc);

  const int tid = threadIdx.x, l = tid & 63, w = tid >> 6;
  const int wm = w >> 1, wn = w & 1, lr = l & 15, q4 = ((l >> 4) & 3) << 2;
  const float* b1e = b1 + (size_t)e * H_ + h0;
  char* Hp = Hpack + (size_t)p * 2097152;
#pragma unroll
  for (int m = 0; m < 4; ++m) {
    const int hl = wm * 64 + m * 16 + q4;           // feature offset (mult of 4)
    const int h = h0 + hl;
    const int uh = h >> 5;
    const int hslot = (h >> 3) & 3;
    const int hbyte = (h & 7) * 2;
    const float4 bias = *(const float4*)(b1e + hl);
#pragma unroll
    for (int n = 0; n < 4; ++n) {
      const int sl = s0 + wn * 64 + n * 16 + lr;    // s row
      ushort4 ov;
      ov.x = __builtin_bit_cast(unsigned short, __float2bfloat16(gelu_fast(acc[m][n][0] + bias.x)));
      ov.y = __builtin_bit_cast(unsigned short, __float2bfloat16(gelu_fast(acc[m][n][1] + bias.y)));
      ov.z = __builtin_bit_cast(unsigned short, __float2bfloat16(gelu_fast(acc[m][n][2] + bias.z)));
      ov.w = __builtin_bit_cast(unsigned short, __float2bfloat16(gelu_fast(acc[m][n][3] + bias.w)));
      const int byte = uh * 32768 + sl * 64 + ((hslot ^ ((sl >> 1) & 3)) << 4) + hbyte;
      *(ushort4*)(Hp + byte) = ov;
    }
  }
}

// ---------------- GEMM2: out += gw * gelu(H @ w2 + b2)  (A = Hpack s-rows) ----------------
// j along s, 16 lanes cover 16 consecutive o -> line-friendly atomics
// (r7/r12-verified: WRITE 65 MB). 2 deterministic f32 atomic terms per output.
__global__ __launch_bounds__(256, 3) void gemm2_kernel(
    const char* __restrict__ Hpack, const char* __restrict__ W2pack,
    const float* __restrict__ b2, float* __restrict__ out,
    const int* __restrict__ gidx, const float* __restrict__ gwt,
    const int* __restrict__ psort)
{
  __shared__ char lds[16384];
  const int P = blockIdx.x;                 // 1024
  const int L = (P & 7) * 128 + (P >> 3);
  const int p = psort[L >> 4];              // 16 tiles/pair, expert-clustered per XCD
  const int tl = L & 15;
  const int b = p >> 1;
  const int e = gidx[p];
  const float gw = gwt[p];
  const int o0 = (tl >> 2) * 128;           // 4 o-tiles (n-axis)
  const int s0 = (tl & 3) * 128;            // 4 s-tiles (m-axis)
  const char* Ag = Hpack + (size_t)p * 2097152 + s0 * 64;   // unit stride 32768
  const char* Bg = W2pack + (size_t)e * 2097152 + o0 * 64;  // unit stride 32768
  f32x4 acc[4][4] = {};
  gemm_core_v10(Ag, Bg, 32768, 32768, H_ / 64, lds, acc);

  const int tid = threadIdx.x, l = tid & 63, w = tid >> 6;
  const int wm = w >> 1, wn = w & 1, lr = l & 15, q4 = ((l >> 4) & 3) << 2;
  const float* b2e = b2 + (size_t)e * O_ + o0;
#pragma unroll
  for (int m = 0; m < 4; ++m) {
    const int sl = s0 + wm * 64 + m * 16 + q4;      // s base for j=0..3
#pragma unroll
    for (int n = 0; n < 4; ++n) {
      const int ol = wn * 64 + n * 16 + lr;         // o (16 consecutive per lane group)
      const float bias = b2e[ol];
      float* dstp = out + ((size_t)b * S_ + sl) * O_ + o0 + ol;
#pragma unroll
      for (int j = 0; j < 4; ++j)
        atomicAdd(dstp + (size_t)j * O_, gelu_fast(acc[m][n][j] + bias) * gw);
    }
  }
}

// ---------------- sentinel (ws too small signal) ----------------
__global__ void sentinel_kernel(float* out, int n) {
  int i = blockIdx.x * blockDim.x + threadIdx.x;
  for (; i < n; i += gridDim.x * blockDim.x) out[i] = 1.0e6f;
}

extern "C" void kernel_launch(void* const* d_in, const int* in_sizes, int n_in,
                              void* d_out, int out_size, void* d_ws, size_t ws_size,
                              hipStream_t stream)
{
  const float* x      = (const float*)d_in[0];
  const float* attn_w = (const float*)d_in[1];
  // d_in[2] = attn_b: scalar, softmax-invariant -> unused
  const float* gate_w = (const float*)d_in[3];
  const float* gate_b = (const float*)d_in[4];
  const float* w1     = (const float*)d_in[5];
  const float* b1     = (const float*)d_in[6];
  const float* w2     = (const float*)d_in[7];
  const float* b2     = (const float*)d_in[8];
  float* out = (float*)d_out;

  char* ws = (char*)d_ws;
  const size_t OFF_GIDX = 0;
  const size_t OFF_GWT  = 256;
  const size_t OFF_PSRT = 512;
  const size_t OFF_X    = 1024;
  const size_t SZ_X     = (size_t)B_ * S_ * D_ * 2;   // 16 MB (xpack)
  const size_t OFF_W1T  = OFF_X + SZ_X;
  const size_t SZ_W1T   = (size_t)E_ * H_ * D_ * 2;   // 16 MB (W1pack)
  const size_t OFF_W2T  = OFF_W1T + SZ_W1T;
  const size_t SZ_W2T   = (size_t)E_ * O_ * H_ * 2;   // 16 MB (W2pack)
  const size_t OFF_H    = OFF_W2T + SZ_W2T;
  const size_t PAIR_H   = (size_t)S_ * H_ * 2;        // 2 MB per pair (Hpack)

  if (OFF_H + 64 * PAIR_H > ws_size) {
    hipLaunchKernelGGL(sentinel_kernel, dim3(256), dim3(256), 0, stream, out, out_size);
    return;
  }

  int*   gidx   = (int*)(ws + OFF_GIDX);
  float* gwt    = (float*)(ws + OFF_GWT);
  int*   psort  = (int*)(ws + OFF_PSRT);
  char*  xpack  = ws + OFF_X;
  char*  W1pack = ws + OFF_W1T;
  char*  W2pack = ws + OFF_W2T;
  char*  Hpack  = ws + OFF_H;
  // pool-chain scratch overlaid on Hpack region (consumed before gemm1 writes it)
  float* scores = (float*)(ws + OFF_H);            // 64 KB
  float* pooled = (float*)(ws + OFF_H + 131072);   // 64 KB

  hipLaunchKernelGGL(cast_score_kernel, dim3(B_ * S_ / 8), dim3(256), 0, stream,
                     x, attn_w, xpack, scores);
  hipLaunchKernelGGL(pool_kernel, dim3(4, B_), dim3(512), 0, stream, x, scores, pooled);
  hipLaunchKernelGGL(gate_psort_kernel, dim3(1), dim3(256), 0, stream,
                     pooled, gate_w, gate_b, gidx, gwt, psort);
  hipLaunchKernelGGL(pack_w_kernel, dim3(H_ / 32, D_ / 32, E_), dim3(32, 8), 0, stream,
                     w1, W1pack, D_, H_);
  hipLaunchKernelGGL(pack_w_kernel, dim3(O_ / 32, H_ / 32, E_), dim3(32, 8), 0, stream,
                     w2, W2pack, H_, O_);
  hipMemsetAsync(d_out, 0, (size_t)out_size * sizeof(float), stream);

  hipLaunchKernelGGL(gemm1_kernel, dim3(4096), dim3(256), 0, stream,
                     xpack, W1pack, b1, Hpack, gidx, psort);
  hipLaunchKernelGGL(gemm2_kernel, dim3(1024), dim3(256), 0, stream,
                     Hpack, W2pack, b2, out, gidx, gwt, psort);
}

// Round 17
// 258.254 us; speedup vs baseline: 1.0566x; 1.0086x over previous
//
#include <hip/hip_runtime.h>
#include <hip/hip_bf16.h>
#include <math.h>

#define B_  32
#define S_  512
#define D_  512
#define E_  8
#define H_  2048
#define O_  512

typedef __bf16 bf16x8 __attribute__((ext_vector_type(8)));
typedef float  f32x4  __attribute__((ext_vector_type(4)));

#define GL2LDS(src, dst) \
  __builtin_amdgcn_global_load_lds((const __attribute__((address_space(1))) void*)(src), \
                                   (__attribute__((address_space(3))) void*)(dst), 16, 0, 0)

#define MFMA16(a, b, c) __builtin_amdgcn_mfma_f32_16x16x32_bf16((a), (b), (c), 0, 0, 0)

// tanh-form GELU (proven r4-r16: absmax 3.9e-3 unchanged)
__device__ __forceinline__ float gelu_fast(float v) {
  float w = v * fmaf(v * v, 0.0713548162f, 1.5957691216f);
  float e = __expf(-w);
  return v * __builtin_amdgcn_rcpf(1.0f + e);
}

// =====================================================================
// Packed operand layout (r8/r9, HW-verified): [z][u = k/32][rows][64B],
// 16B slot within each 64B row pre-swizzled: phys_slot = ks ^ ((row>>1)&3).
// A 128-row slice of one u-unit is contiguous 8 KB.
// =====================================================================

// ---------------- cast x -> packed bf16 (xpack), fused attention scores ----
__global__ __launch_bounds__(256) void cast_score_kernel(
    const float* __restrict__ x, const float* __restrict__ attn_w,
    char* __restrict__ xpack, float* __restrict__ scores)
{
  const int t = threadIdx.x;
  const int r = t >> 5;
  const int cg = t & 31;
  const int row = blockIdx.x * 8 + r;     // global b*512+s
  const int bb = row >> 9, s = row & 511;
  const float* src  = x + (size_t)row * D_ + cg * 16;
  const float* wsrc = attn_w + cg * 16;
  char* xp = xpack + (size_t)bb * 524288 + s * 64;
  const int sx = (s >> 1) & 3;
  float acc = 0.f;
#pragma unroll
  for (int k = 0; k < 4; ++k) {
    const int d0 = cg * 16 + k * 4;
    float4 v  = *(const float4*)(src + k * 4);
    float4 wv = *(const float4*)(wsrc + k * 4);
    acc += v.x * wv.x + v.y * wv.y + v.z * wv.z + v.w * wv.w;
    ushort4 o;
    o.x = __builtin_bit_cast(unsigned short, __float2bfloat16(v.x));
    o.y = __builtin_bit_cast(unsigned short, __float2bfloat16(v.y));
    o.z = __builtin_bit_cast(unsigned short, __float2bfloat16(v.z));
    o.w = __builtin_bit_cast(unsigned short, __float2bfloat16(v.w));
    const int u = d0 >> 5;
    const int byte = u * 32768 + ((((d0 >> 3) & 3) ^ sx) << 4) + (d0 & 7) * 2;
    *(ushort4*)(xp + byte) = o;
  }
#pragma unroll
  for (int off = 16; off; off >>= 1) acc += __shfl_xor(acc, off);
  if (cg == 0) scores[row] = acc;
}

// ---------------- pool with inline softmax (r15/r16, verified) ----------------
__global__ __launch_bounds__(512) void pool_kernel(
    const float* __restrict__ x, const float* __restrict__ scores,
    float* __restrict__ pooled)
{
  __shared__ float awsh[512];
  __shared__ float red[8];
  __shared__ float mm, ss;
  __shared__ float sm[4][128];
  const int t = threadIdx.x;
  const int b = blockIdx.y;
  float v = scores[b * S_ + t];
  float m = v;
#pragma unroll
  for (int off = 32; off; off >>= 1) m = fmaxf(m, __shfl_xor(m, off));
  if ((t & 63) == 0) red[t >> 6] = m;
  __syncthreads();
  if (t == 0) {
    float a = red[0];
    for (int i = 1; i < 8; ++i) a = fmaxf(a, red[i]);
    mm = a;
  }
  __syncthreads();
  float e = expf(v - mm);
  float s = e;
#pragma unroll
  for (int off = 32; off; off >>= 1) s += __shfl_xor(s, off);
  if ((t & 63) == 0) red[t >> 6] = s;
  __syncthreads();
  if (t == 0) {
    float a = 0.f;
    for (int i = 0; i < 8; ++i) a += red[i];
    ss = 1.f / a;
  }
  __syncthreads();
  awsh[t] = e * ss;
  __syncthreads();

  const int dl = t & 127;
  const int sh = t >> 7;
  const int d = blockIdx.x * 128 + dl;
  const float* xp = x + (size_t)b * S_ * D_ + d;
  float acc = 0.f;
#pragma unroll 4
  for (int s2 = sh; s2 < S_; s2 += 4)
    acc = fmaf(awsh[s2], xp[(size_t)s2 * D_], acc);
  if (sh) sm[sh][dl] = acc;
  __syncthreads();
  if (sh == 0) pooled[b * D_ + d] = acc + sm[1][dl] + sm[2][dl] + sm[3][dl];
}

// ---------------- gates + top-2 + renorm + expert-sort ----------------
__global__ __launch_bounds__(256) void gate_psort_kernel(
    const float* __restrict__ pooled, const float* __restrict__ gate_w,
    const float* __restrict__ gate_b, int* __restrict__ gidx, float* __restrict__ gwt,
    int* __restrict__ psort)
{
  __shared__ float gl[32][8];
  const int t = threadIdx.x;
  const int b = t >> 3, ee = t & 7;
  float z = gate_b[ee];
  const float* pb = pooled + b * D_;
  for (int d = 0; d < D_; ++d) z = fmaf(pb[d], gate_w[d * E_ + ee], z);
  gl[b][ee] = z;
  __syncthreads();
  if (t < 32) {
    float ge[8];
    float zmax = gl[t][0];
    for (int i = 1; i < 8; ++i) zmax = fmaxf(zmax, gl[t][i]);
    float zs = 0.f;
    for (int i = 0; i < 8; ++i) { ge[i] = expf(gl[t][i] - zmax); zs += ge[i]; }
    for (int i = 0; i < 8; ++i) ge[i] /= zs;
    int i0 = 0;
    for (int i = 1; i < 8; ++i) if (ge[i] > ge[i0]) i0 = i;
    int i1 = -1;
    for (int i = 0; i < 8; ++i) if (i != i0 && (i1 < 0 || ge[i] > ge[i1])) i1 = i;
    float denom = ge[i0] + ge[i1] + 1e-9f;
    gidx[t * 2 + 0] = i0; gidx[t * 2 + 1] = i1;
    gwt[t * 2 + 0] = ge[i0] / denom; gwt[t * 2 + 1] = ge[i1] / denom;
  }
  __syncthreads();
  if (t == 0) {
    int cnt[E_] = {}, pos[E_];
    for (int p = 0; p < 2 * B_; ++p) cnt[gidx[p]]++;
    int s = 0;
    for (int e2 = 0; e2 < E_; ++e2) { pos[e2] = s; s += cnt[e2]; }
    for (int p = 0; p < 2 * B_; ++p) psort[pos[gidx[p]]++] = p;
  }
}

// ---------------- weight pack: [z][R k][C rows] f32 -> packed bf16 ----------------
__global__ void pack_w_kernel(const float* __restrict__ in, char* __restrict__ outp,
                              int R, int C)
{
  __shared__ float tile[32][33];
  const int z = blockIdx.z;
  const float* inz = in + (size_t)z * R * C;
  const int c0 = blockIdx.x * 32, r0 = blockIdx.y * 32;
  const int tx = threadIdx.x, ty = threadIdx.y;
#pragma unroll
  for (int jj = 0; jj < 4; ++jj) {
    int r = r0 + ty + jj * 8;
    tile[ty + jj * 8][tx] = inz[(size_t)r * C + c0 + tx];
  }
  __syncthreads();
  const int k = r0 + tx;
  const int u = k >> 5;                                 // constant over tile
  const int PAN = C * 64;
  char* oz = outp + (size_t)z * R * C * 2 + (size_t)u * PAN;
  const int kslot = (k >> 3) & 3;
  const int kbyte = (k & 7) * 2;
#pragma unroll
  for (int jj = 0; jj < 4; ++jj) {
    const int row = c0 + ty + jj * 8;
    const int byte = row * 64 + ((kslot ^ ((row >> 1) & 3)) << 4) + kbyte;
    *(ushort*)(oz + byte) =
        __builtin_bit_cast(unsigned short, __float2bfloat16(tile[tx][ty + jj * 8]));
  }
}

// =====================================================================
// GEMM core v11: r16's A-LDS/B-reg structure + 1-tile prefetch inside the
// 3-block residency regime. 128x128xBK=64, 4 waves (wm=w>>1, wn=w&1),
// acc[4][4]. A: 2 x 16KB ping-pong LDS; B: two NAMED reg sets (rule #20),
// unroll-by-2 loop. Per tile 12 VMEM {4 A-GL2LDS + 8 B-loads}; counted
// vmcnt(12) at tile head = drain tile t (issued one full tile earlier),
// keep t+1's 12 in flight. Tail -> vmcnt(0). WAR: STAGE(t+2 -> buf just
// freed by the tile's closing barrier). launch_bounds(256,3): ~3 blocks/CU.
// Read swizzle phys_slot = ks ^ ((lr>>1)&3).
// =====================================================================
__device__ __forceinline__ void gemm_core_v11(const char* __restrict__ Ag, const char* __restrict__ Bg,
                                              const size_t unitA, const size_t unitB,
                                              const int NT, char* lds, f32x4 (&acc)[4][4])
{
  const int tid = threadIdx.x;
  const int l = tid & 63;
  const int w = tid >> 6;
  const int wm = w >> 1;
  const int wn = w & 1;
  const int lr = l & 15;
  const int ks = (l >> 4) & 3;
  const int swz = ((ks ^ ((lr >> 1) & 3)) << 4);
  const int abase = wm * 4096 + lr * 64 + swz;            // + m*1024 + kh*8192
  const int bloff = (wn * 64 + lr) * 64 + swz;            // + n*1024 within unit
  const int dst = tid * 16;

#define V11_STAGE_A(t_, Lb) { \
    const char* a0_ = Ag + (size_t)(2 * (t_)) * unitA; \
    const char* a1_ = Ag + (size_t)(2 * (t_) + 1) * unitA; \
    GL2LDS(a0_ + dst, (Lb) + dst);          GL2LDS(a0_ + 4096 + dst, (Lb) + 4096 + dst); \
    GL2LDS(a1_ + dst, (Lb) + 8192 + dst);   GL2LDS(a1_ + 4096 + dst, (Lb) + 12288 + dst); }

#define V11_LOAD_B(t_, bv) { \
    const char* b0_ = Bg + (size_t)(2 * (t_)) * unitB + bloff; \
    const char* b1_ = Bg + (size_t)(2 * (t_) + 1) * unitB + bloff; \
    _Pragma("unroll") \
    for (int n = 0; n < 4; ++n) { \
      bv[0][n] = *(const bf16x8*)(b0_ + n * 1024); \
      bv[1][n] = *(const bf16x8*)(b1_ + n * 1024); } }

#define V11_COMPUTE(Lb, bv) { \
    bf16x8 a0f_[4], a1f_[4]; \
    _Pragma("unroll") \
    for (int m = 0; m < 4; ++m) { \
      a0f_[m] = *(const bf16x8*)((Lb) + abase + m * 1024); \
      a1f_[m] = *(const bf16x8*)((Lb) + 8192 + abase + m * 1024); } \
    _Pragma("unroll") \
    for (int m = 0; m < 4; ++m) \
      _Pragma("unroll") \
      for (int n = 0; n < 4; ++n) { \
        acc[m][n] = MFMA16(a0f_[m], bv[0][n], acc[m][n]); \
        acc[m][n] = MFMA16(a1f_[m], bv[1][n], acc[m][n]); } }

  char* buf0 = lds;
  char* buf1 = lds + 16384;
  bf16x8 bv0[2][4], bv1[2][4];

  // prologue: tiles 0 and 1
  V11_STAGE_A(0, buf0); V11_LOAD_B(0, bv0);
  V11_STAGE_A(1, buf1); V11_LOAD_B(1, bv1);

#pragma unroll 1
  for (int t = 0; t < NT; t += 2) {
    const bool pre = (t + 2 < NT);
    // ---- even tile t: buf0 / bv0 ----
    asm volatile("s_waitcnt vmcnt(12)" ::: "memory");   // t's 12 drained (t+1 in flight)
    __builtin_amdgcn_s_barrier();
    V11_COMPUTE(buf0, bv0);
    __builtin_amdgcn_s_barrier();                       // buf0 reads done
    if (pre) { V11_STAGE_A(t + 2, buf0); V11_LOAD_B(t + 2, bv0); }
    // ---- odd tile t+1: buf1 / bv1 ----
    if (pre) asm volatile("s_waitcnt vmcnt(12)" ::: "memory");
    else     asm volatile("s_waitcnt vmcnt(0)" ::: "memory");
    __builtin_amdgcn_s_barrier();
    V11_COMPUTE(buf1, bv1);
    __builtin_amdgcn_s_barrier();                       // buf1 reads done
    if (pre) { V11_STAGE_A(t + 3, buf1); V11_LOAD_B(t + 3, bv1); }
  }
#undef V11_STAGE_A
#undef V11_LOAD_B
#undef V11_COMPUTE
}

// ---------------- GEMM1: Hpack = gelu(x @ w1 + b1)  (A = W1 h-rows) ----------------
__global__ __launch_bounds__(256, 3) void gemm1_kernel(
    const char* __restrict__ xpack, const char* __restrict__ W1pack,
    const float* __restrict__ b1, char* __restrict__ Hpack,
    const int* __restrict__ gidx, const int* __restrict__ psort)
{
  __shared__ char lds[32768];
  const int P = blockIdx.x;                 // 4096
  const int L = (P & 7) * 512 + (P >> 3);   // bijective XCD chunk remap
  const int p = psort[L >> 6];              // 64 tiles/pair, pair-clustered per XCD
  const int tl = L & 63;
  const int b = p >> 1;
  const int e = gidx[p];
  const int h0 = (tl >> 2) * 128;           // 16 h-tiles
  const int s0 = (tl & 3) * 128;            // 4 s-tiles
  const char* Ag = W1pack + (size_t)e * 2097152 + h0 * 64;  // unit stride 131072
  const char* Bg = xpack + (size_t)b * 524288 + s0 * 64;    // unit stride 32768
  f32x4 acc[4][4] = {};
  gemm_core_v11(Ag, Bg, 131072, 32768, D_ / 64, lds, acc);

  const int tid = threadIdx.x, l = tid & 63, w = tid >> 6;
  const int wm = w >> 1, wn = w & 1, lr = l & 15, q4 = ((l >> 4) & 3) << 2;
  const float* b1e = b1 + (size_t)e * H_ + h0;
  char* Hp = Hpack + (size_t)p * 2097152;
#pragma unroll
  for (int m = 0; m < 4; ++m) {
    const int hl = wm * 64 + m * 16 + q4;           // feature offset (mult of 4)
    const int h = h0 + hl;
    const int uh = h >> 5;
    const int hslot = (h >> 3) & 3;
    const int hbyte = (h & 7) * 2;
    const float4 bias = *(const float4*)(b1e + hl);
#pragma unroll
    for (int n = 0; n < 4; ++n) {
      const int sl = s0 + wn * 64 + n * 16 + lr;    // s row
      ushort4 ov;
      ov.x = __builtin_bit_cast(unsigned short, __float2bfloat16(gelu_fast(acc[m][n][0] + bias.x)));
      ov.y = __builtin_bit_cast(unsigned short, __float2bfloat16(gelu_fast(acc[m][n][1] + bias.y)));
      ov.z = __builtin_bit_cast(unsigned short, __float2bfloat16(gelu_fast(acc[m][n][2] + bias.z)));
      ov.w = __builtin_bit_cast(unsigned short, __float2bfloat16(gelu_fast(acc[m][n][3] + bias.w)));
      const int byte = uh * 32768 + sl * 64 + ((hslot ^ ((sl >> 1) & 3)) << 4) + hbyte;
      *(ushort4*)(Hp + byte) = ov;
    }
  }
}

// ---------------- GEMM2: out += gw * gelu(H @ w2 + b2)  (A = Hpack s-rows) ----------------
// j along s, 16 lanes cover 16 consecutive o -> line-friendly atomics
// (r7/r12-verified: WRITE 65 MB). 2 deterministic f32 atomic terms per output.
__global__ __launch_bounds__(256, 3) void gemm2_kernel(
    const char* __restrict__ Hpack, const char* __restrict__ W2pack,
    const float* __restrict__ b2, float* __restrict__ out,
    const int* __restrict__ gidx, const float* __restrict__ gwt,
    const int* __restrict__ psort)
{
  __shared__ char lds[32768];
  const int P = blockIdx.x;                 // 1024
  const int L = (P & 7) * 128 + (P >> 3);
  const int p = psort[L >> 4];              // 16 tiles/pair, expert-clustered per XCD
  const int tl = L & 15;
  const int b = p >> 1;
  const int e = gidx[p];
  const float gw = gwt[p];
  const int o0 = (tl >> 2) * 128;           // 4 o-tiles (n-axis)
  const int s0 = (tl & 3) * 128;            // 4 s-tiles (m-axis)
  const char* Ag = Hpack + (size_t)p * 2097152 + s0 * 64;   // unit stride 32768
  const char* Bg = W2pack + (size_t)e * 2097152 + o0 * 64;  // unit stride 32768
  f32x4 acc[4][4] = {};
  gemm_core_v11(Ag, Bg, 32768, 32768, H_ / 64, lds, acc);

  const int tid = threadIdx.x, l = tid & 63, w = tid >> 6;
  const int wm = w >> 1, wn = w & 1, lr = l & 15, q4 = ((l >> 4) & 3) << 2;
  const float* b2e = b2 + (size_t)e * O_ + o0;
#pragma unroll
  for (int m = 0; m < 4; ++m) {
    const int sl = s0 + wm * 64 + m * 16 + q4;      // s base for j=0..3
#pragma unroll
    for (int n = 0; n < 4; ++n) {
      const int ol = wn * 64 + n * 16 + lr;         // o (16 consecutive per lane group)
      const float bias = b2e[ol];
      float* dstp = out + ((size_t)b * S_ + sl) * O_ + o0 + ol;
#pragma unroll
      for (int j = 0; j < 4; ++j)
        atomicAdd(dstp + (size_t)j * O_, gelu_fast(acc[m][n][j] + bias) * gw);
    }
  }
}

// ---------------- sentinel (ws too small signal) ----------------
__global__ void sentinel_kernel(float* out, int n) {
  int i = blockIdx.x * blockDim.x + threadIdx.x;
  for (; i < n; i += gridDim.x * blockDim.x) out[i] = 1.0e6f;
}

extern "C" void kernel_launch(void* const* d_in, const int* in_sizes, int n_in,
                              void* d_out, int out_size, void* d_ws, size_t ws_size,
                              hipStream_t stream)
{
  const float* x      = (const float*)d_in[0];
  const float* attn_w = (const float*)d_in[1];
  // d_in[2] = attn_b: scalar, softmax-invariant -> unused
  const float* gate_w = (const float*)d_in[3];
  const float* gate_b = (const float*)d_in[4];
  const float* w1     = (const float*)d_in[5];
  const float* b1     = (const float*)d_in[6];
  const float* w2     = (const float*)d_in[7];
  const float* b2     = (const float*)d_in[8];
  float* out = (float*)d_out;

  char* ws = (char*)d_ws;
  const size_t OFF_GIDX = 0;
  const size_t OFF_GWT  = 256;
  const size_t OFF_PSRT = 512;
  const size_t OFF_X    = 1024;
  const size_t SZ_X     = (size_t)B_ * S_ * D_ * 2;   // 16 MB (xpack)
  const size_t OFF_W1T  = OFF_X + SZ_X;
  const size_t SZ_W1T   = (size_t)E_ * H_ * D_ * 2;   // 16 MB (W1pack)
  const size_t OFF_W2T  = OFF_W1T + SZ_W1T;
  const size_t SZ_W2T   = (size_t)E_ * O_ * H_ * 2;   // 16 MB (W2pack)
  const size_t OFF_H    = OFF_W2T + SZ_W2T;
  const size_t PAIR_H   = (size_t)S_ * H_ * 2;        // 2 MB per pair (Hpack)

  if (OFF_H + 64 * PAIR_H > ws_size) {
    hipLaunchKernelGGL(sentinel_kernel, dim3(256), dim3(256), 0, stream, out, out_size);
    return;
  }

  int*   gidx   = (int*)(ws + OFF_GIDX);
  float* gwt    = (float*)(ws + OFF_GWT);
  int*   psort  = (int*)(ws + OFF_PSRT);
  char*  xpack  = ws + OFF_X;
  char*  W1pack = ws + OFF_W1T;
  char*  W2pack = ws + OFF_W2T;
  char*  Hpack  = ws + OFF_H;
  // pool-chain scratch overlaid on Hpack region (consumed before gemm1 writes it)
  float* scores = (float*)(ws + OFF_H);            // 64 KB
  float* pooled = (float*)(ws + OFF_H + 131072);   // 64 KB

  hipLaunchKernelGGL(cast_score_kernel, dim3(B_ * S_ / 8), dim3(256), 0, stream,
                     x, attn_w, xpack, scores);
  hipLaunchKernelGGL(pool_kernel, dim3(4, B_), dim3(512), 0, stream, x, scores, pooled);
  hipLaunchKernelGGL(gate_psort_kernel, dim3(1), dim3(256), 0, stream,
                     pooled, gate_w, gate_b, gidx, gwt, psort);
  hipLaunchKernelGGL(pack_w_kernel, dim3(H_ / 32, D_ / 32, E_), dim3(32, 8), 0, stream,
                     w1, W1pack, D_, H_);
  hipLaunchKernelGGL(pack_w_kernel, dim3(O_ / 32, H_ / 32, E_), dim3(32, 8), 0, stream,
                     w2, W2pack, H_, O_);
  hipMemsetAsync(d_out, 0, (size_t)out_size * sizeof(float), stream);

  hipLaunchKernelGGL(gemm1_kernel, dim3(4096), dim3(256), 0, stream,
                     xpack, W1pack, b1, Hpack, gidx, psort);
  hipLaunchKernelGGL(gemm2_kernel, dim3(1024), dim3(256), 0, stream,
                     Hpack, W2pack, b2, out, gidx, gwt, psort);
}

// Round 18
// 252.891 us; speedup vs baseline: 1.0790x; 1.0212x over previous
//
#include <hip/hip_runtime.h>
#include <hip/hip_bf16.h>
#include <math.h>

#define B_  32
#define S_  512
#define D_  512
#define E_  8
#define H_  2048
#define O_  512

typedef __bf16 bf16x8 __attribute__((ext_vector_type(8)));
typedef float  f32x4  __attribute__((ext_vector_type(4)));

#define GL2LDS(src, dst) \
  __builtin_amdgcn_global_load_lds((const __attribute__((address_space(1))) void*)(src), \
                                   (__attribute__((address_space(3))) void*)(dst), 16, 0, 0)

#define MFMA16(a, b, c) __builtin_amdgcn_mfma_f32_16x16x32_bf16((a), (b), (c), 0, 0, 0)

// tanh-form GELU (proven r4-r17: absmax 3.9e-3 unchanged)
__device__ __forceinline__ float gelu_fast(float v) {
  float w = v * fmaf(v * v, 0.0713548162f, 1.5957691216f);
  float e = __expf(-w);
  return v * __builtin_amdgcn_rcpf(1.0f + e);
}

// =====================================================================
// Packed operand layout (r8/r9, HW-verified): [z][u = k/32][rows][64B],
// 16B slot within each 64B row pre-swizzled: phys_slot = ks ^ ((row>>1)&3).
// A 128-row slice of one u-unit is contiguous 8 KB.
// =====================================================================

// ---------------- fused prep: cast_score + pack_w1 + pack_w2 ----------------
// Three independent prep stages merged into one launch so they co-schedule
// (they were serial, each under-filling the chip). Bodies are r17-verbatim.
__device__ __forceinline__ void cast_score_body(
    int bid, int tid, const float* __restrict__ x, const float* __restrict__ attn_w,
    char* __restrict__ xpack, float* __restrict__ scores)
{
  const int r = tid >> 5;
  const int cg = tid & 31;
  const int row = bid * 8 + r;            // global b*512+s
  const int bb = row >> 9, s = row & 511;
  const float* src  = x + (size_t)row * D_ + cg * 16;
  const float* wsrc = attn_w + cg * 16;
  char* xp = xpack + (size_t)bb * 524288 + s * 64;
  const int sx = (s >> 1) & 3;
  float acc = 0.f;
#pragma unroll
  for (int k = 0; k < 4; ++k) {
    const int d0 = cg * 16 + k * 4;
    float4 v  = *(const float4*)(src + k * 4);
    float4 wv = *(const float4*)(wsrc + k * 4);
    acc += v.x * wv.x + v.y * wv.y + v.z * wv.z + v.w * wv.w;
    ushort4 o;
    o.x = __builtin_bit_cast(unsigned short, __float2bfloat16(v.x));
    o.y = __builtin_bit_cast(unsigned short, __float2bfloat16(v.y));
    o.z = __builtin_bit_cast(unsigned short, __float2bfloat16(v.z));
    o.w = __builtin_bit_cast(unsigned short, __float2bfloat16(v.w));
    const int u = d0 >> 5;
    const int byte = u * 32768 + ((((d0 >> 3) & 3) ^ sx) << 4) + (d0 & 7) * 2;
    *(ushort4*)(xp + byte) = o;
  }
#pragma unroll
  for (int off = 16; off; off >>= 1) acc += __shfl_xor(acc, off);
  if (cg == 0) scores[row] = acc;
}

__device__ __forceinline__ void pack_w_body(
    int bx, int by, int z, int tid, const float* __restrict__ in,
    char* __restrict__ outp, int R, int C, float* __restrict__ tile /*[32][33]*/)
{
  const int tx = tid & 31, ty = tid >> 5;   // (32,8)
  const float* inz = in + (size_t)z * R * C;
  const int c0 = bx * 32, r0 = by * 32;
#pragma unroll
  for (int jj = 0; jj < 4; ++jj) {
    int r = r0 + ty + jj * 8;
    tile[(ty + jj * 8) * 33 + tx] = inz[(size_t)r * C + c0 + tx];
  }
  __syncthreads();
  const int k = r0 + tx;
  const int u = k >> 5;
  const int PAN = C * 64;
  char* oz = outp + (size_t)z * R * C * 2 + (size_t)u * PAN;
  const int kslot = (k >> 3) & 3;
  const int kbyte = (k & 7) * 2;
#pragma unroll
  for (int jj = 0; jj < 4; ++jj) {
    const int row = c0 + ty + jj * 8;
    const int byte = row * 64 + ((kslot ^ ((row >> 1) & 3)) << 4) + kbyte;
    *(ushort*)(oz + byte) =
        __builtin_bit_cast(unsigned short, __float2bfloat16(tile[tx * 33 + ty + jj * 8]));
  }
}

// grid: [0,2048) cast_score | [2048,10240) pack_w1 | [10240,18432) pack_w2
__global__ __launch_bounds__(256) void prep_kernel(
    const float* __restrict__ x, const float* __restrict__ attn_w,
    const float* __restrict__ w1, const float* __restrict__ w2,
    char* __restrict__ xpack, char* __restrict__ W1pack, char* __restrict__ W2pack,
    float* __restrict__ scores)
{
  __shared__ float tile[32 * 33];
  const int P = blockIdx.x;
  const int tid = threadIdx.x;
  if (P < 2048) {
    cast_score_body(P, tid, x, attn_w, xpack, scores);
  } else if (P < 10240) {
    const int idx = P - 2048;             // pack_w1: R=D=512, C=H=2048; bx<64, by<16
    const int z = idx >> 10;
    const int r2 = idx & 1023;
    pack_w_body(r2 & 63, r2 >> 6, z, tid, w1, W1pack, D_, H_, tile);
  } else {
    const int idx = P - 10240;            // pack_w2: R=H=2048, C=O=512; bx<16, by<64
    const int z = idx >> 10;
    const int r2 = idx & 1023;
    pack_w_body(r2 & 15, r2 >> 4, z, tid, w2, W2pack, H_, O_, tile);
  }
}

// ---------------- pool with inline softmax (r15-r17, verified) ----------------
__global__ __launch_bounds__(512) void pool_kernel(
    const float* __restrict__ x, const float* __restrict__ scores,
    float* __restrict__ pooled)
{
  __shared__ float awsh[512];
  __shared__ float red[8];
  __shared__ float mm, ss;
  __shared__ float sm[4][128];
  const int t = threadIdx.x;
  const int b = blockIdx.y;
  float v = scores[b * S_ + t];
  float m = v;
#pragma unroll
  for (int off = 32; off; off >>= 1) m = fmaxf(m, __shfl_xor(m, off));
  if ((t & 63) == 0) red[t >> 6] = m;
  __syncthreads();
  if (t == 0) {
    float a = red[0];
    for (int i = 1; i < 8; ++i) a = fmaxf(a, red[i]);
    mm = a;
  }
  __syncthreads();
  float e = expf(v - mm);
  float s = e;
#pragma unroll
  for (int off = 32; off; off >>= 1) s += __shfl_xor(s, off);
  if ((t & 63) == 0) red[t >> 6] = s;
  __syncthreads();
  if (t == 0) {
    float a = 0.f;
    for (int i = 0; i < 8; ++i) a += red[i];
    ss = 1.f / a;
  }
  __syncthreads();
  awsh[t] = e * ss;
  __syncthreads();

  const int dl = t & 127;
  const int sh = t >> 7;
  const int d = blockIdx.x * 128 + dl;
  const float* xp = x + (size_t)b * S_ * D_ + d;
  float acc = 0.f;
#pragma unroll 4
  for (int s2 = sh; s2 < S_; s2 += 4)
    acc = fmaf(awsh[s2], xp[(size_t)s2 * D_], acc);
  if (sh) sm[sh][dl] = acc;
  __syncthreads();
  if (sh == 0) pooled[b * D_ + d] = acc + sm[1][dl] + sm[2][dl] + sm[3][dl];
}

// ---------------- gates + top-2 + renorm + expert-sort ----------------
__global__ __launch_bounds__(256) void gate_psort_kernel(
    const float* __restrict__ pooled, const float* __restrict__ gate_w,
    const float* __restrict__ gate_b, int* __restrict__ gidx, float* __restrict__ gwt,
    int* __restrict__ psort)
{
  __shared__ float gl[32][8];
  const int t = threadIdx.x;
  const int b = t >> 3, ee = t & 7;
  float z = gate_b[ee];
  const float* pb = pooled + b * D_;
  for (int d = 0; d < D_; ++d) z = fmaf(pb[d], gate_w[d * E_ + ee], z);
  gl[b][ee] = z;
  __syncthreads();
  if (t < 32) {
    float ge[8];
    float zmax = gl[t][0];
    for (int i = 1; i < 8; ++i) zmax = fmaxf(zmax, gl[t][i]);
    float zs = 0.f;
    for (int i = 0; i < 8; ++i) { ge[i] = expf(gl[t][i] - zmax); zs += ge[i]; }
    for (int i = 0; i < 8; ++i) ge[i] /= zs;
    int i0 = 0;
    for (int i = 1; i < 8; ++i) if (ge[i] > ge[i0]) i0 = i;
    int i1 = -1;
    for (int i = 0; i < 8; ++i) if (i != i0 && (i1 < 0 || ge[i] > ge[i1])) i1 = i;
    float denom = ge[i0] + ge[i1] + 1e-9f;
    gidx[t * 2 + 0] = i0; gidx[t * 2 + 1] = i1;
    gwt[t * 2 + 0] = ge[i0] / denom; gwt[t * 2 + 1] = ge[i1] / denom;
  }
  __syncthreads();
  if (t == 0) {
    int cnt[E_] = {}, pos[E_];
    for (int p = 0; p < 2 * B_; ++p) cnt[gidx[p]]++;
    int s = 0;
    for (int e2 = 0; e2 < E_; ++e2) { pos[e2] = s; s += cnt[e2]; }
    for (int p = 0; p < 2 * B_; ++p) psort[pos[gidx[p]]++] = p;
  }
}

// =====================================================================
// GEMM core v11 (r17): A-LDS(2x16KB ping-pong via GL2LDS) + B-regs (named
// sets), 1-tile prefetch, counted vmcnt(12), 3-block residency target.
// 128x128xBK=64, 4 waves (wm=w>>1, wn=w&1), acc[4][4].
// Read swizzle phys_slot = ks ^ ((lr>>1)&3).
// =====================================================================
__device__ __forceinline__ void gemm_core_v11(const char* __restrict__ Ag, const char* __restrict__ Bg,
                                              const size_t unitA, const size_t unitB,
                                              const int NT, char* lds, f32x4 (&acc)[4][4])
{
  const int tid = threadIdx.x;
  const int l = tid & 63;
  const int w = tid >> 6;
  const int wm = w >> 1;
  const int wn = w & 1;
  const int lr = l & 15;
  const int ks = (l >> 4) & 3;
  const int swz = ((ks ^ ((lr >> 1) & 3)) << 4);
  const int abase = wm * 4096 + lr * 64 + swz;            // + m*1024 + kh*8192
  const int bloff = (wn * 64 + lr) * 64 + swz;            // + n*1024 within unit
  const int dst = tid * 16;

#define V11_STAGE_A(t_, Lb) { \
    const char* a0_ = Ag + (size_t)(2 * (t_)) * unitA; \
    const char* a1_ = Ag + (size_t)(2 * (t_) + 1) * unitA; \
    GL2LDS(a0_ + dst, (Lb) + dst);          GL2LDS(a0_ + 4096 + dst, (Lb) + 4096 + dst); \
    GL2LDS(a1_ + dst, (Lb) + 8192 + dst);   GL2LDS(a1_ + 4096 + dst, (Lb) + 12288 + dst); }

#define V11_LOAD_B(t_, bv) { \
    const char* b0_ = Bg + (size_t)(2 * (t_)) * unitB + bloff; \
    const char* b1_ = Bg + (size_t)(2 * (t_) + 1) * unitB + bloff; \
    _Pragma("unroll") \
    for (int n = 0; n < 4; ++n) { \
      bv[0][n] = *(const bf16x8*)(b0_ + n * 1024); \
      bv[1][n] = *(const bf16x8*)(b1_ + n * 1024); } }

#define V11_COMPUTE(Lb, bv) { \
    bf16x8 a0f_[4], a1f_[4]; \
    _Pragma("unroll") \
    for (int m = 0; m < 4; ++m) { \
      a0f_[m] = *(const bf16x8*)((Lb) + abase + m * 1024); \
      a1f_[m] = *(const bf16x8*)((Lb) + 8192 + abase + m * 1024); } \
    _Pragma("unroll") \
    for (int m = 0; m < 4; ++m) \
      _Pragma("unroll") \
      for (int n = 0; n < 4; ++n) { \
        acc[m][n] = MFMA16(a0f_[m], bv[0][n], acc[m][n]); \
        acc[m][n] = MFMA16(a1f_[m], bv[1][n], acc[m][n]); } }

  char* buf0 = lds;
  char* buf1 = lds + 16384;
  bf16x8 bv0[2][4], bv1[2][4];

  V11_STAGE_A(0, buf0); V11_LOAD_B(0, bv0);
  V11_STAGE_A(1, buf1); V11_LOAD_B(1, bv1);

#pragma unroll 1
  for (int t = 0; t < NT; t += 2) {
    const bool pre = (t + 2 < NT);
    asm volatile("s_waitcnt vmcnt(12)" ::: "memory");
    __builtin_amdgcn_s_barrier();
    V11_COMPUTE(buf0, bv0);
    __builtin_amdgcn_s_barrier();
    if (pre) { V11_STAGE_A(t + 2, buf0); V11_LOAD_B(t + 2, bv0); }
    if (pre) asm volatile("s_waitcnt vmcnt(12)" ::: "memory");
    else     asm volatile("s_waitcnt vmcnt(0)" ::: "memory");
    __builtin_amdgcn_s_barrier();
    V11_COMPUTE(buf1, bv1);
    __builtin_amdgcn_s_barrier();
    if (pre) { V11_STAGE_A(t + 3, buf1); V11_LOAD_B(t + 3, bv1); }
  }
#undef V11_STAGE_A
#undef V11_LOAD_B
#undef V11_COMPUTE
}

// ---------------- GEMM1: Hpack = gelu(x @ w1 + b1)  (A = W1 h-rows) ----------------
__global__ __launch_bounds__(256, 3) void gemm1_kernel(
    const char* __restrict__ xpack, const char* __restrict__ W1pack,
    const float* __restrict__ b1, char* __restrict__ Hpack,
    const int* __restrict__ gidx, const int* __restrict__ psort)
{
  __shared__ char lds[32768];
  const int P = blockIdx.x;                 // 4096
  const int L = (P & 7) * 512 + (P >> 3);   // bijective XCD chunk remap
  const int p = psort[L >> 6];              // 64 tiles/pair, pair-clustered per XCD
  const int tl = L & 63;
  const int b = p >> 1;
  const int e = gidx[p];
  const int h0 = (tl >> 2) * 128;           // 16 h-tiles
  const int s0 = (tl & 3) * 128;            // 4 s-tiles
  const char* Ag = W1pack + (size_t)e * 2097152 + h0 * 64;  // unit stride 131072
  const char* Bg = xpack + (size_t)b * 524288 + s0 * 64;    // unit stride 32768
  f32x4 acc[4][4] = {};
  gemm_core_v11(Ag, Bg, 131072, 32768, D_ / 64, lds, acc);

  const int tid = threadIdx.x, l = tid & 63, w = tid >> 6;
  const int wm = w >> 1, wn = w & 1, lr = l & 15, q4 = ((l >> 4) & 3) << 2;
  const float* b1e = b1 + (size_t)e * H_ + h0;
  char* Hp = Hpack + (size_t)p * 2097152;
#pragma unroll
  for (int m = 0; m < 4; ++m) {
    const int hl = wm * 64 + m * 16 + q4;           // feature offset (mult of 4)
    const int h = h0 + hl;
    const int uh = h >> 5;
    const int hslot = (h >> 3) & 3;
    const int hbyte = (h & 7) * 2;
    const float4 bias = *(const float4*)(b1e + hl);
#pragma unroll
    for (int n = 0; n < 4; ++n) {
      const int sl = s0 + wn * 64 + n * 16 + lr;    // s row
      ushort4 ov;
      ov.x = __builtin_bit_cast(unsigned short, __float2bfloat16(gelu_fast(acc[m][n][0] + bias.x)));
      ov.y = __builtin_bit_cast(unsigned short, __float2bfloat16(gelu_fast(acc[m][n][1] + bias.y)));
      ov.z = __builtin_bit_cast(unsigned short, __float2bfloat16(gelu_fast(acc[m][n][2] + bias.z)));
      ov.w = __builtin_bit_cast(unsigned short, __float2bfloat16(gelu_fast(acc[m][n][3] + bias.w)));
      const int byte = uh * 32768 + sl * 64 + ((hslot ^ ((sl >> 1) & 3)) << 4) + hbyte;
      *(ushort4*)(Hp + byte) = ov;
    }
  }
}

// ---------------- GEMM2: out += gw * gelu(H @ w2 + b2)  (A = Hpack s-rows) ----------------
__global__ __launch_bounds__(256, 3) void gemm2_kernel(
    const char* __restrict__ Hpack, const char* __restrict__ W2pack,
    const float* __restrict__ b2, float* __restrict__ out,
    const int* __restrict__ gidx, const float* __restrict__ gwt,
    const int* __restrict__ psort)
{
  __shared__ char lds[32768];
  const int P = blockIdx.x;                 // 1024
  const int L = (P & 7) * 128 + (P >> 3);
  const int p = psort[L >> 4];              // 16 tiles/pair, expert-clustered per XCD
  const int tl = L & 15;
  const int b = p >> 1;
  const int e = gidx[p];
  const float gw = gwt[p];
  const int o0 = (tl >> 2) * 128;           // 4 o-tiles (n-axis)
  const int s0 = (tl & 3) * 128;            // 4 s-tiles (m-axis)
  const char* Ag = Hpack + (size_t)p * 2097152 + s0 * 64;   // unit stride 32768
  const char* Bg = W2pack + (size_t)e * 2097152 + o0 * 64;  // unit stride 32768
  f32x4 acc[4][4] = {};
  gemm_core_v11(Ag, Bg, 32768, 32768, H_ / 64, lds, acc);

  const int tid = threadIdx.x, l = tid & 63, w = tid >> 6;
  const int wm = w >> 1, wn = w & 1, lr = l & 15, q4 = ((l >> 4) & 3) << 2;
  const float* b2e = b2 + (size_t)e * O_ + o0;
#pragma unroll
  for (int m = 0; m < 4; ++m) {
    const int sl = s0 + wm * 64 + m * 16 + q4;      // s base for j=0..3
#pragma unroll
    for (int n = 0; n < 4; ++n) {
      const int ol = wn * 64 + n * 16 + lr;         // o (16 consecutive per lane group)
      const float bias = b2e[ol];
      float* dstp = out + ((size_t)b * S_ + sl) * O_ + o0 + ol;
#pragma unroll
      for (int j = 0; j < 4; ++j)
        atomicAdd(dstp + (size_t)j * O_, gelu_fast(acc[m][n][j] + bias) * gw);
    }
  }
}

// ---------------- sentinel (ws too small signal) ----------------
__global__ void sentinel_kernel(float* out, int n) {
  int i = blockIdx.x * blockDim.x + threadIdx.x;
  for (; i < n; i += gridDim.x * blockDim.x) out[i] = 1.0e6f;
}

extern "C" void kernel_launch(void* const* d_in, const int* in_sizes, int n_in,
                              void* d_out, int out_size, void* d_ws, size_t ws_size,
                              hipStream_t stream)
{
  const float* x      = (const float*)d_in[0];
  const float* attn_w = (const float*)d_in[1];
  // d_in[2] = attn_b: scalar, softmax-invariant -> unused
  const float* gate_w = (const float*)d_in[3];
  const float* gate_b = (const float*)d_in[4];
  const float* w1     = (const float*)d_in[5];
  const float* b1     = (const float*)d_in[6];
  const float* w2     = (const float*)d_in[7];
  const float* b2     = (const float*)d_in[8];
  float* out = (float*)d_out;

  char* ws = (char*)d_ws;
  const size_t OFF_GIDX = 0;
  const size_t OFF_GWT  = 256;
  const size_t OFF_PSRT = 512;
  const size_t OFF_X    = 1024;
  const size_t SZ_X     = (size_t)B_ * S_ * D_ * 2;   // 16 MB (xpack)
  const size_t OFF_W1T  = OFF_X + SZ_X;
  const size_t SZ_W1T   = (size_t)E_ * H_ * D_ * 2;   // 16 MB (W1pack)
  const size_t OFF_W2T  = OFF_W1T + SZ_W1T;
  const size_t SZ_W2T   = (size_t)E_ * O_ * H_ * 2;   // 16 MB (W2pack)
  const size_t OFF_H    = OFF_W2T + SZ_W2T;
  const size_t PAIR_H   = (size_t)S_ * H_ * 2;        // 2 MB per pair (Hpack)

  if (OFF_H + 64 * PAIR_H > ws_size) {
    hipLaunchKernelGGL(sentinel_kernel, dim3(256), dim3(256), 0, stream, out, out_size);
    return;
  }

  int*   gidx   = (int*)(ws + OFF_GIDX);
  float* gwt    = (float*)(ws + OFF_GWT);
  int*   psort  = (int*)(ws + OFF_PSRT);
  char*  xpack  = ws + OFF_X;
  char*  W1pack = ws + OFF_W1T;
  char*  W2pack = ws + OFF_W2T;
  char*  Hpack  = ws + OFF_H;
  // pool-chain scratch overlaid on Hpack region (consumed before gemm1 writes it)
  float* scores = (float*)(ws + OFF_H);            // 64 KB
  float* pooled = (float*)(ws + OFF_H + 131072);   // 64 KB

  hipLaunchKernelGGL(prep_kernel, dim3(18432), dim3(256), 0, stream,
                     x, attn_w, w1, w2, xpack, W1pack, W2pack, scores);
  hipLaunchKernelGGL(pool_kernel, dim3(4, B_), dim3(512), 0, stream, x, scores, pooled);
  hipLaunchKernelGGL(gate_psort_kernel, dim3(1), dim3(256), 0, stream,
                     pooled, gate_w, gate_b, gidx, gwt, psort);
  hipMemsetAsync(d_out, 0, (size_t)out_size * sizeof(float), stream);

  hipLaunchKernelGGL(gemm1_kernel, dim3(4096), dim3(256), 0, stream,
                     xpack, W1pack, b1, Hpack, gidx, psort);
  hipLaunchKernelGGL(gemm2_kernel, dim3(1024), dim3(256), 0, stream,
                     Hpack, W2pack, b2, out, gidx, gwt, psort);
}